// Round 7
// baseline (733.870 us; speedup 1.0000x reference)
//
#include <hip/hip_runtime.h>

#define NLVL 16
#define NDENSE 7            // levels 0..6: (res+1)^3 < 2^19 -> densify
#define PREPASS_CAP 600000  // max dense entries the pre-pass covers

typedef float f32x2 __attribute__((ext_vector_type(2)));
typedef float f32x4 __attribute__((ext_vector_type(4)));

__device__ __forceinline__ unsigned hash3(unsigned x, unsigned y, unsigned z) {
    return x ^ (y * 2654435761u) ^ (z * 805459861u);
}

__device__ __forceinline__ unsigned dense_total(const int* __restrict__ resolutions,
                                                unsigned doff[NDENSE]) {
    unsigned acc = 0;
    for (int ll = 0; ll < NDENSE; ++ll) {
        unsigned S = (unsigned)resolutions[ll] + 1u;
        doff[ll] = acc;
        acc += S * S * S;
    }
    return acc;
}

// ---- pre-pass: copy hashed coarse tables into dense 3D arrays in ws ----
__global__ __launch_bounds__(256) void densify_kernel(
    const float* __restrict__ emb,
    const int*   __restrict__ offsets,
    const int*   __restrict__ resolutions,
    float*       __restrict__ ws)
{
    unsigned doff[NDENSE];
    unsigned total = dense_total(resolutions, doff);
    if (total > PREPASS_CAP) total = PREPASS_CAP;
    unsigned tid = blockIdx.x * 256u + threadIdx.x;
    if (tid >= total) return;
    int l = 0;
    while (l < NDENSE - 1 && tid >= doff[l + 1]) ++l;
    unsigned idx = tid - doff[l];
    unsigned S = (unsigned)resolutions[l] + 1u;
    unsigned x = idx % S;
    unsigned t = idx / S;
    unsigned y = t % S;
    unsigned z = t / S;
    unsigned off  = (unsigned)offsets[l];
    unsigned size = (unsigned)offsets[l + 1] - off;
    unsigned mask = size - 1u;
    unsigned h = hash3(x, y, z);
    unsigned hm = ((size & mask) == 0u) ? (h & mask) : (h % size);
    const f32x2* src = reinterpret_cast<const f32x2*>(emb) + off + hm;
    f32x2* dst = reinterpret_cast<f32x2*>(ws) + tid;
    *dst = *src;
}

// ---- main: one block = one level x 256 points ----
// Static map (R5): g<8 -> fine level 8+g pinned on XCD g; g==8 -> level 7
// (XCD0); g>8 -> dense coarse level g-9 (XCD1..7).
// Fine levels use the x-pair trick: hash = x ^ f(y,z) with x unmultiplied and
// pow2 table size, so for even x the corners (x, x+1) land in one aligned
// 16B pair -> one load serves both. Odd-x lanes issue one extra 8B load.
__global__ __launch_bounds__(256) void encode_kernel(
    const float* __restrict__ xyz,
    const float* __restrict__ emb,
    const int*   __restrict__ offsets,
    const int*   __restrict__ resolutions,
    const float* __restrict__ min_xyz,
    const float* __restrict__ max_xyz,
    const float* __restrict__ dense,
    float*       __restrict__ out,
    int B, int use_dense)
{
    const int g = blockIdx.x & 15;
    const int chunk = blockIdx.x >> 4;
    const int l = (g < 8) ? (8 + g) : ((g == 8) ? 7 : (g - 9));
    const int p = chunk * 256 + (int)threadIdx.x;
    if (p >= B) return;

    const float res = (float)resolutions[l];
    const unsigned off  = (unsigned)offsets[l];
    const unsigned size = (unsigned)offsets[l + 1] - off;
    const unsigned mask = size - 1u;
    const bool pow2 = (size & mask) == 0u;
    const float mn0 = min_xyz[0], mn1 = min_xyz[1], mn2 = min_xyz[2];
    const float mx0 = max_xyz[0], mx1 = max_xyz[1], mx2 = max_xyz[2];

    // nontemporal xyz: this stream is re-read 16x per dispatch; keep it from
    // evicting the pinned embedding tables in L2
    const float x = __builtin_nontemporal_load(xyz + (size_t)p * 3 + 0);
    const float y = __builtin_nontemporal_load(xyz + (size_t)p * 3 + 1);
    const float z = __builtin_nontemporal_load(xyz + (size_t)p * 3 + 2);
    // bit-exact fp32 chain (matches reference op order)
    const float ux = (x - mn0) / (mx0 - mn0);
    const float uy = (y - mn1) / (mx1 - mn1);
    const float uz = (z - mn2) / (mx2 - mn2);
    const bool valid = (ux >= 0.0f) & (ux <= 1.0f) &
                       (uy >= 0.0f) & (uy <= 1.0f) &
                       (uz >= 0.0f) & (uz <= 1.0f);

    const float rm1 = res - 1.0f;
    const float px = ux * res, py = uy * res, pz = uz * res;
    const float p0x = fminf(fmaxf(floorf(px), 0.0f), rm1);
    const float p0y = fminf(fmaxf(floorf(py), 0.0f), rm1);
    const float p0z = fminf(fmaxf(floorf(pz), 0.0f), rm1);
    const float fx = px - p0x, fy = py - p0y, fz = pz - p0z;
    const float gx = 1.0f - fx, gy = 1.0f - fy, gz = 1.0f - fz;
    const unsigned cx0 = (unsigned)p0x;
    const unsigned cy0 = (unsigned)p0y;
    const unsigned cz0 = (unsigned)p0z;

    float o0 = 0.0f, o1 = 0.0f;

    bool dense_ok = false;
    unsigned doff[NDENSE];
    if (use_dense && l < NDENSE) {
        unsigned total = dense_total(resolutions, doff);
        dense_ok = (total <= PREPASS_CAP);
    }

    if (dense_ok) {
        const unsigned S = (unsigned)resolutions[l] + 1u;
        const f32x2* lvl = reinterpret_cast<const f32x2*>(dense) + doff[l];
        const unsigned base = cx0 + S * (cy0 + S * cz0);
        f32x4 e00, e10, e01, e11;
        __builtin_memcpy(&e00, lvl + base,             16);
        __builtin_memcpy(&e10, lvl + base + S,         16);
        __builtin_memcpy(&e01, lvl + base + S * S,     16);
        __builtin_memcpy(&e11, lvl + base + S * S + S, 16);
        o0 += (gx * gy * gz) * e00.x;  o1 += (gx * gy * gz) * e00.y;  // c=0
        o0 += (fx * gy * gz) * e00.z;  o1 += (fx * gy * gz) * e00.w;  // c=1
        o0 += (gx * fy * gz) * e10.x;  o1 += (gx * fy * gz) * e10.y;  // c=2
        o0 += (fx * fy * gz) * e10.z;  o1 += (fx * fy * gz) * e10.w;  // c=3
        o0 += (gx * gy * fz) * e01.x;  o1 += (gx * gy * fz) * e01.y;  // c=4
        o0 += (fx * gy * fz) * e01.z;  o1 += (fx * gy * fz) * e01.w;  // c=5
        o0 += (gx * fy * fz) * e11.x;  o1 += (gx * fy * fz) * e11.y;  // c=6
        o0 += (fx * fy * fz) * e11.z;  o1 += (fx * fy * fz) * e11.w;  // c=7
    } else if (pow2) {
        // hashed fine level, x-pair merge
        const f32x2* lvl = reinterpret_cast<const f32x2*>(emb) + off;
        f32x4 E[4];
        unsigned h0a[4], h1a[4];
#pragma unroll
        for (int pi = 0; pi < 4; ++pi) {
            unsigned by = (unsigned)(pi & 1);
            unsigned bz = (unsigned)(pi >> 1);
            unsigned m = ((cy0 + by) * 2654435761u) ^ ((cz0 + bz) * 805459861u);
            unsigned h0 = (cx0 ^ m) & mask;          // corner bx=0
            unsigned h1 = ((cx0 + 1u) ^ m) & mask;   // corner bx=1
            h0a[pi] = h0; h1a[pi] = h1;
            // aligned 16B pair containing h0 (and h0^1)
            __builtin_memcpy(&E[pi], lvl + (h0 & ~1u), 16);
        }
        f32x2 e1v[4];
        if (cx0 & 1u) {
            // odd x: bx=1 corner is in a different pair -> 4 extra 8B loads
#pragma unroll
            for (int pi = 0; pi < 4; ++pi) e1v[pi] = lvl[h1a[pi]];
        } else {
            // even x: h1 = h0^1, other half of the same 16B pair
#pragma unroll
            for (int pi = 0; pi < 4; ++pi) {
                f32x2 lo; lo.x = E[pi].x; lo.y = E[pi].y;
                f32x2 hi; hi.x = E[pi].z; hi.y = E[pi].w;
                e1v[pi] = (h0a[pi] & 1u) ? lo : hi;
            }
        }
#pragma unroll
        for (int pi = 0; pi < 4; ++pi) {
            unsigned by = (unsigned)(pi & 1);
            unsigned bz = (unsigned)(pi >> 1);
            float wy = by ? fy : gy;
            float wz = bz ? fz : gz;
            float wyz = wy * wz;
            f32x2 lo; lo.x = E[pi].x; lo.y = E[pi].y;
            f32x2 hi; hi.x = E[pi].z; hi.y = E[pi].w;
            f32x2 e0 = (h0a[pi] & 1u) ? hi : lo;     // corner bx=0
            f32x2 e1 = e1v[pi];                      // corner bx=1
            float w0 = gx * wyz;
            float w1 = fx * wyz;
            o0 += w0 * e0.x;  o1 += w0 * e0.y;       // c = 2*by+4*bz
            o0 += w1 * e1.x;  o1 += w1 * e1.y;       // c = 2*by+4*bz+1
        }
    } else {
        // generic fallback (non-pow2 table size)
        const f32x2* lvl = reinterpret_cast<const f32x2*>(emb) + off;
#pragma unroll
        for (int c = 0; c < 8; ++c) {
            unsigned bx = (unsigned)(c & 1);
            unsigned by = (unsigned)((c >> 1) & 1);
            unsigned bz = (unsigned)((c >> 2) & 1);
            unsigned h = hash3(cx0 + bx, cy0 + by, cz0 + bz);
            unsigned hm = h % size;
            f32x2 e = lvl[hm];
            float w = (bx ? fx : gx) * (by ? fy : gy);
            w = w * (bz ? fz : gz);
            o0 += w * e.x;
            o1 += w * e.y;
        }
    }

    if (!valid) { o0 = 0.0f; o1 = 0.0f; }
    f32x2 r; r.x = o0; r.y = o1;
    f32x2* op = reinterpret_cast<f32x2*>(out + (size_t)p * (NLVL * 2) + l * 2);
    __builtin_nontemporal_store(r, op);
}

extern "C" void kernel_launch(void* const* d_in, const int* in_sizes, int n_in,
                              void* d_out, int out_size, void* d_ws, size_t ws_size,
                              hipStream_t stream) {
    const float* xyz        = (const float*)d_in[0];
    const float* embeddings = (const float*)d_in[1];
    const int*   offsets    = (const int*)d_in[2];
    const int*   resolutions= (const int*)d_in[3];
    const float* min_xyz    = (const float*)d_in[4];
    const float* max_xyz    = (const float*)d_in[5];
    float* out = (float*)d_out;

    int B = in_sizes[0] / 3;
    int use_dense = (ws_size >= (size_t)PREPASS_CAP * 8) ? 1 : 0;

    if (use_dense) {
        int pgrid = (PREPASS_CAP + 255) / 256;
        densify_kernel<<<pgrid, 256, 0, stream>>>(
            embeddings, offsets, resolutions, (float*)d_ws);
    }
    int nchunks = (B + 255) / 256;
    int grid = nchunks * NLVL;
    encode_kernel<<<grid, 256, 0, stream>>>(
        xyz, embeddings, offsets, resolutions, min_xyz, max_xyz,
        (const float*)d_ws, out, B, use_dense);
}

// Round 8
// 645.653 us; speedup vs baseline: 1.1366x; 1.1366x over previous
//
#include <hip/hip_runtime.h>

#define NLVL 16
#define NDENSE 7            // levels 0..6: (res+1)^3 < 2^19 -> densify
#define PREPASS_CAP 600000  // max dense entries the pre-pass covers

typedef float f32x2 __attribute__((ext_vector_type(2)));
typedef float f32x4 __attribute__((ext_vector_type(4)));

__device__ __forceinline__ unsigned hash3(unsigned x, unsigned y, unsigned z) {
    return x ^ (y * 2654435761u) ^ (z * 805459861u);
}

__device__ __forceinline__ unsigned dense_total(const int* __restrict__ resolutions,
                                                unsigned doff[NDENSE]) {
    unsigned acc = 0;
    for (int ll = 0; ll < NDENSE; ++ll) {
        unsigned S = (unsigned)resolutions[ll] + 1u;
        doff[ll] = acc;
        acc += S * S * S;
    }
    return acc;
}

// ---- pre-pass: copy hashed coarse tables into dense 3D arrays ----
__global__ __launch_bounds__(256) void densify_kernel(
    const float* __restrict__ emb,
    const int*   __restrict__ offsets,
    const int*   __restrict__ resolutions,
    float*       __restrict__ dense)
{
    unsigned doff[NDENSE];
    unsigned total = dense_total(resolutions, doff);
    if (total > PREPASS_CAP) total = PREPASS_CAP;
    unsigned tid = blockIdx.x * 256u + threadIdx.x;
    if (tid >= total) return;
    int l = 0;
    while (l < NDENSE - 1 && tid >= doff[l + 1]) ++l;
    unsigned idx = tid - doff[l];
    unsigned S = (unsigned)resolutions[l] + 1u;
    unsigned x = idx % S;
    unsigned t = idx / S;
    unsigned y = t % S;
    unsigned z = t / S;
    unsigned off  = (unsigned)offsets[l];
    unsigned size = (unsigned)offsets[l + 1] - off;
    unsigned mask = size - 1u;
    unsigned h = hash3(x, y, z);
    unsigned hm = ((size & mask) == 0u) ? (h & mask) : (h % size);
    const f32x2* src = reinterpret_cast<const f32x2*>(emb) + off + hm;
    f32x2* dst = reinterpret_cast<f32x2*>(dense) + tid;
    *dst = *src;
}

// ---- main: one block = one level x 256 points (R5 static map) ----
// g<8 -> fine level 8+g pinned on XCD g; g==8 -> level 7; g>8 -> dense level g-9.
// Stores go COALESCED to level-major scratch[l*B+p] (8B/lane consecutive);
// a separate transpose kernel produces out[p][l].
__global__ __launch_bounds__(256) void encode_kernel(
    const float* __restrict__ xyz,
    const float* __restrict__ emb,
    const int*   __restrict__ offsets,
    const int*   __restrict__ resolutions,
    const float* __restrict__ min_xyz,
    const float* __restrict__ max_xyz,
    const float* __restrict__ dense,
    float*       __restrict__ scratch,
    float*       __restrict__ out,
    int B, int use_dense, int use_scratch)
{
    const int g = blockIdx.x & 15;
    const int chunk = blockIdx.x >> 4;
    const int l = (g < 8) ? (8 + g) : ((g == 8) ? 7 : (g - 9));
    const int p = chunk * 256 + (int)threadIdx.x;
    if (p >= B) return;

    const float res = (float)resolutions[l];
    const unsigned off  = (unsigned)offsets[l];
    const unsigned size = (unsigned)offsets[l + 1] - off;
    const unsigned mask = size - 1u;
    const bool pow2 = (size & mask) == 0u;
    const float mn0 = min_xyz[0], mn1 = min_xyz[1], mn2 = min_xyz[2];
    const float mx0 = max_xyz[0], mx1 = max_xyz[1], mx2 = max_xyz[2];

    const float x = xyz[p * 3 + 0];
    const float y = xyz[p * 3 + 1];
    const float z = xyz[p * 3 + 2];
    // bit-exact fp32 chain (matches reference op order)
    const float ux = (x - mn0) / (mx0 - mn0);
    const float uy = (y - mn1) / (mx1 - mn1);
    const float uz = (z - mn2) / (mx2 - mn2);
    const bool valid = (ux >= 0.0f) & (ux <= 1.0f) &
                       (uy >= 0.0f) & (uy <= 1.0f) &
                       (uz >= 0.0f) & (uz <= 1.0f);

    const float rm1 = res - 1.0f;
    const float px = ux * res, py = uy * res, pz = uz * res;
    const float p0x = fminf(fmaxf(floorf(px), 0.0f), rm1);
    const float p0y = fminf(fmaxf(floorf(py), 0.0f), rm1);
    const float p0z = fminf(fmaxf(floorf(pz), 0.0f), rm1);
    const float fx = px - p0x, fy = py - p0y, fz = pz - p0z;
    const float gx = 1.0f - fx, gy = 1.0f - fy, gz = 1.0f - fz;
    const unsigned cx0 = (unsigned)p0x;
    const unsigned cy0 = (unsigned)p0y;
    const unsigned cz0 = (unsigned)p0z;

    float o0 = 0.0f, o1 = 0.0f;

    bool dense_ok = false;
    unsigned doff[NDENSE];
    if (use_dense && l < NDENSE) {
        unsigned total = dense_total(resolutions, doff);
        dense_ok = (total <= PREPASS_CAP);
    }

    if (dense_ok) {
        const unsigned S = (unsigned)resolutions[l] + 1u;
        const f32x2* lvl = reinterpret_cast<const f32x2*>(dense) + doff[l];
        const unsigned base = cx0 + S * (cy0 + S * cz0);
        f32x4 e00, e10, e01, e11;
        __builtin_memcpy(&e00, lvl + base,             16);
        __builtin_memcpy(&e10, lvl + base + S,         16);
        __builtin_memcpy(&e01, lvl + base + S * S,     16);
        __builtin_memcpy(&e11, lvl + base + S * S + S, 16);
        o0 += (gx * gy * gz) * e00.x;  o1 += (gx * gy * gz) * e00.y;  // c=0
        o0 += (fx * gy * gz) * e00.z;  o1 += (fx * gy * gz) * e00.w;  // c=1
        o0 += (gx * fy * gz) * e10.x;  o1 += (gx * fy * gz) * e10.y;  // c=2
        o0 += (fx * fy * gz) * e10.z;  o1 += (fx * fy * gz) * e10.w;  // c=3
        o0 += (gx * gy * fz) * e01.x;  o1 += (gx * gy * fz) * e01.y;  // c=4
        o0 += (fx * gy * fz) * e01.z;  o1 += (fx * gy * fz) * e01.w;  // c=5
        o0 += (gx * fy * fz) * e11.x;  o1 += (gx * fy * fz) * e11.y;  // c=6
        o0 += (fx * fy * fz) * e11.z;  o1 += (fx * fy * fz) * e11.w;  // c=7
    } else {
        const f32x2* lvl = reinterpret_cast<const f32x2*>(emb) + off;
#pragma unroll
        for (int c = 0; c < 8; ++c) {
            unsigned bx = (unsigned)(c & 1);
            unsigned by = (unsigned)((c >> 1) & 1);
            unsigned bz = (unsigned)((c >> 2) & 1);
            unsigned h = hash3(cx0 + bx, cy0 + by, cz0 + bz);
            unsigned hm = pow2 ? (h & mask) : (h % size);
            f32x2 e = lvl[hm];
            float w = (bx ? fx : gx) * (by ? fy : gy);
            w = w * (bz ? fz : gz);
            o0 += w * e.x;
            o1 += w * e.y;
        }
    }

    if (!valid) { o0 = 0.0f; o1 = 0.0f; }
    f32x2 r; r.x = o0; r.y = o1;
    if (use_scratch) {
        // coalesced: lanes write consecutive p at fixed l
        f32x2* op = reinterpret_cast<f32x2*>(scratch) + (size_t)l * B + p;
        __builtin_nontemporal_store(r, op);
    } else {
        f32x2* op = reinterpret_cast<f32x2*>(out + (size_t)p * (NLVL * 2) + l * 2);
        __builtin_nontemporal_store(r, op);
    }
}

// ---- transpose scratch[l][p] -> out[p][l] via LDS tile ----
// block = 64 points x 16 levels, 256 threads.
__global__ __launch_bounds__(256) void transpose_kernel(
    const float* __restrict__ scratch,
    float*       __restrict__ out,
    int B)
{
    __shared__ float tile[64][33];   // [point][2*l(+1)] with pad: conflict-free
    const int p0 = blockIdx.x * 64;
    const int tid = (int)threadIdx.x;

    const f32x2* src = reinterpret_cast<const f32x2*>(scratch);
#pragma unroll
    for (int k = 0; k < 4; ++k) {
        int it = tid + k * 256;      // 0..1023
        int l  = it >> 6;
        int pi = it & 63;
        int p  = p0 + pi;
        f32x2 v = (p < B) ? src[(size_t)l * B + p] : (f32x2){0.0f, 0.0f};
        tile[pi][2 * l]     = v.x;
        tile[pi][2 * l + 1] = v.y;
    }
    __syncthreads();

    const int pl = tid >> 2;        // 0..63
    const int q  = tid & 3;         // 0..3 -> 8-float (32B) chunk
    const int p  = p0 + pl;
    if (p >= B) return;
    float vals[8];
#pragma unroll
    for (int j = 0; j < 8; ++j) vals[j] = tile[pl][q * 8 + j];
    f32x4 lo, hi;
    lo.x = vals[0]; lo.y = vals[1]; lo.z = vals[2]; lo.w = vals[3];
    hi.x = vals[4]; hi.y = vals[5]; hi.z = vals[6]; hi.w = vals[7];
    f32x4* dst = reinterpret_cast<f32x4*>(out + (size_t)p * 32 + q * 8);
    __builtin_nontemporal_store(lo, dst);
    __builtin_nontemporal_store(hi, dst + 1);
}

extern "C" void kernel_launch(void* const* d_in, const int* in_sizes, int n_in,
                              void* d_out, int out_size, void* d_ws, size_t ws_size,
                              hipStream_t stream) {
    const float* xyz        = (const float*)d_in[0];
    const float* embeddings = (const float*)d_in[1];
    const int*   offsets    = (const int*)d_in[2];
    const int*   resolutions= (const int*)d_in[3];
    const float* min_xyz    = (const float*)d_in[4];
    const float* max_xyz    = (const float*)d_in[5];
    float* out = (float*)d_out;

    int B = in_sizes[0] / 3;
    size_t scratch_bytes = (size_t)B * NLVL * 8;          // f32x2 per (l,p)
    size_t dense_bytes   = (size_t)PREPASS_CAP * 8;

    int use_scratch = (ws_size >= scratch_bytes + dense_bytes) ? 1 : 0;
    size_t dense_off = use_scratch ? scratch_bytes : 0;
    int use_dense = (ws_size >= dense_off + dense_bytes) ? 1 : 0;

    float* scratch  = (float*)d_ws;
    float* dense_p  = (float*)((char*)d_ws + dense_off);

    if (use_dense) {
        int pgrid = (PREPASS_CAP + 255) / 256;
        densify_kernel<<<pgrid, 256, 0, stream>>>(
            embeddings, offsets, resolutions, dense_p);
    }
    int nchunks = (B + 255) / 256;
    int grid = nchunks * NLVL;
    encode_kernel<<<grid, 256, 0, stream>>>(
        xyz, embeddings, offsets, resolutions, min_xyz, max_xyz,
        dense_p, scratch, out, B, use_dense, use_scratch);
    if (use_scratch) {
        int tgrid = (B + 63) / 64;
        transpose_kernel<<<tgrid, 256, 0, stream>>>(scratch, out, B);
    }
}